// Round 9
// baseline (26.937 us; speedup 1.0000x reference)
//
#include <hip/hip_runtime.h>
#include <math.h>

namespace {

constexpr int NX  = 512;    // data points
constexpr int M   = 514;    // basis functions
constexpr int NE  = 8192;   // eval points
constexpr int NBC = 256;    // batch*channels
constexpr int WARM = 14;    // warm-up rows (rel err ~0.268^14 ~ 1e-8 -> far below 9e-2 threshold)

constexpr int NBLK = 1024;  // one block per 8 eval points -> 4 blocks/CU exactly
constexpr int PPB  = NE / NBLK;     // 8
constexpr int SLOTS  = 37;  // staged Z columns per bc row (>= NRr+3 = 36; 37 covers z511 corner)
constexpr int STRIDE = 39;  // odd -> conflict-free; LDS = 256*39*4 = 39.9 KB -> 4 blocks/CU

// ---------------------------------------------------------------------------
// Compile-time tables: basis weights and banded Cholesky factor (double math).
// ---------------------------------------------------------------------------
constexpr double dknot(int j) {
    int c = j - 3;
    c = c < 0 ? 0 : (c > NX - 1 ? NX - 1 : c);
    return -1.0 + 2.0 * (double)c / 511.0;
}

constexpr double csqrt(double x) {
    double r = x > 1.0 ? x : 1.0;
    for (int k = 0; k < 50; ++k) r = 0.5 * (r + x / r);
    return r;
}

struct Tables {
    alignas(16) float lb[M + 3][4];  // rd=1/diag, l1, l2, l3 (3 zero pad rows)
    alignas(16) float w4[M][4];      // w4[i][r] = weight of Z[i-r] in Btz[i] (0 if OOR)
    float we[4];                     // weight of Z[511] in Btz[510+q]
};

constexpr Tables make_tables() {
    Tables T{};
    double bx[NX][4] = {};
    for (int n = 0; n < NX; ++n) {
        const int off = n < NX - 1 ? n : NX - 2;
        const double x = -1.0 + 2.0 * (double)n / 511.0;
        double N[4] = {1.0, 0.0, 0.0, 0.0};
        for (int d = 1; d <= 3; ++d) {
            double saved = 0.0;
            for (int r = 0; r < d; ++r) {
                const double tr = dknot(off + 3 + r + 1);
                const double tl = dknot(off + 3 + r + 1 - d);
                const double temp = N[r] / (tr - tl);
                N[r] = saved + (tr - x) * temp;
                saved = (x - tl) * temp;
            }
            N[d] = saved;
        }
        for (int r = 0; r < 4; ++r) bx[n][r] = N[r];
    }
    double A[M][4] = {};
    for (int i = 0; i < M; ++i) {
        double a0 = 1e-3, a1 = 0.0, a2 = 0.0, a3 = 0.0;
        const int nlo = i - 3 < 0 ? 0 : i - 3;
        const int nhi = i + 1 > NX - 1 ? NX - 1 : i + 1;
        for (int n = nlo; n <= nhi; ++n) {
            const int off = n < NX - 1 ? n : NX - 2;
            const int ri = i - off;
            if (ri < 0 || ri > 3) continue;
            const double bi = bx[n][ri];
            a0 += bi * bx[n][ri];
            if (ri >= 1) a1 += bi * bx[n][ri - 1];
            if (ri >= 2) a2 += bi * bx[n][ri - 2];
            if (ri >= 3) a3 += bi * bx[n][ri - 3];
        }
        A[i][0] = a0; A[i][1] = a1; A[i][2] = a2; A[i][3] = a3;
    }
    {
        double rd1 = 0.0, l1p = 0.0, l2p = 0.0, rd2 = 0.0, l1pp = 0.0, rd3 = 0.0;
        for (int i = 0; i < M; ++i) {
            const double l3 = A[i][3] * rd3;
            const double l2 = (A[i][2] - l3 * l1pp) * rd2;
            const double l1 = (A[i][1] - l3 * l2p - l2 * l1p) * rd1;
            const double s  = A[i][0] - l3 * l3 - l2 * l2 - l1 * l1;
            const double rd = 1.0 / csqrt(s);
            T.lb[i][0] = (float)rd; T.lb[i][1] = (float)l1;
            T.lb[i][2] = (float)l2; T.lb[i][3] = (float)l3;
            rd3 = rd2; rd2 = rd1; rd1 = rd;
            l1pp = l1p; l1p = l1; l2p = l2;
        }
    }
    for (int i = 0; i < M; ++i)
        for (int r = 0; r < 4; ++r) {
            const int n = i - r;
            T.w4[i][r] = (n >= 0 && n <= NX - 2) ? (float)bx[n][r] : 0.0f;
        }
    for (int q = 0; q < 4; ++q) T.we[q] = (float)bx[NX - 1][q];
    return T;
}

__constant__ Tables TBL = make_tables();

// interior (Toeplitz / converged) constants as compile-time immediates
constexpr Tables HT = make_tables();
constexpr float CW0 = HT.w4[256][0], CW1 = HT.w4[256][1], CW2 = HT.w4[256][2], CW3 = HT.w4[256][3];
constexpr float CRD = HT.lb[256][0], CL1 = HT.lb[256][1], CL2 = HT.lb[256][2], CL3 = HT.lb[256][3];
constexpr int INT_LO = 48, INT_HI = 462;

// interval index of eval point n (single fp32 path everywhere)
__device__ __forceinline__ int offf(int n) {
    const float xe = -1.0f + 2.0f * (float)n / 8191.0f;
    int off = (int)((xe + 1.0f) * 255.5f);
    return off < 0 ? 0 : (off > NX - 2 ? NX - 2 : off);
}

__device__ __forceinline__ float knotf(int j) {
    int c = j - 3;
    c = c < 0 ? 0 : (c > NX - 1 ? NX - 1 : c);
    return -1.0f + 2.0f * (float)c / 511.0f;
}

__device__ __forceinline__ void deboor3(float x, int j, float N[4]) {
    N[0] = 1.0f; N[1] = 0.0f; N[2] = 0.0f; N[3] = 0.0f;
#pragma unroll
    for (int d = 1; d <= 3; ++d) {
        float saved = 0.0f;
#pragma unroll
        for (int r = 0; r < 3; ++r) {
            if (r < d) {
                const float tr = knotf(j + r + 1);
                const float tl = knotf(j + r + 1 - d);
                const float temp = N[r] / (tr - tl);
                N[r] = saved + (tr - x) * temp;
                saved = (x - tl) * temp;
            }
        }
        N[d] = saved;
    }
}

// ---------------------------------------------------------------------------
// Single fused kernel. Block b handles eval points [b*8, b*8+8) x all 256 bc.
// Stage the Z window (coalesced, pipelined) into LDS (row per bc, stride 39),
// run warm-up fwd+bwd banded substitution per-lane in LDS (slot i-i0 holds
// Z col i-3 -> y_i -> coef_i as data dies), then evaluate from LDS coef with
// 2 float4 stores per thread (thread = bc row). 39.9 KB LDS -> 4 blocks/CU.
// ---------------------------------------------------------------------------
__global__ __launch_bounds__(256) void spline_fused(const float* __restrict__ Z,
                                                    float* __restrict__ out) {
    __shared__ float Bs[NBC * STRIDE + 8];   // +8 pad for fwd over-read
    const int tid = threadIdx.x;
    const int b = blockIdx.x;
    const int ns = b * PPB;

    // wave-uniform geometry
    const int e_lo = offf(ns);                    // first coef row eval needs
    const int e_hi = offf(ns + PPB - 1) + 3;      // last coef row eval needs
    int i0 = e_lo - WARM;  i0 = i0 < 0 ? 0 : i0;  // forward start (exact if 0)
    int i_end = e_hi + WARM;  i_end = i_end > M - 1 ? M - 1 : i_end;
    const int n0 = i0 - 3;                        // first staged Z column
    const int NRr = i_end - i0 + 1;               // forward rows  (<= 33)
    const int NRb = i_end - e_lo + 1;             // backward rows (<= 19)

    // ---- stage Z[bc][n0 .. n0+SLOTS) -> Bs[bc][slot], coalesced, pipelined --
    const int wid = tid >> 6, lane = tid & 63;
    {
        int ja = n0 + lane;
        ja = ja < 0 ? 0 : (ja > NX - 1 ? NX - 1 : ja);   // OOR taps have zero weight
        const bool on = lane < SLOTS;

#define LOADG(p, kk)                                                       \
        { const float* zp = Z + (size_t)((wid << 6) + (kk)) * NX;          \
          if (on) { p##0 = zp[ja];          p##1 = zp[NX + ja];            \
                    p##2 = zp[2 * NX + ja]; p##3 = zp[3 * NX + ja]; } }
#define WRITEG(p, kk)                                                      \
        { float* wp = Bs + ((wid << 6) + (kk)) * STRIDE;                   \
          if (on) { wp[lane] = p##0;              wp[STRIDE + lane] = p##1; \
                    wp[2 * STRIDE + lane] = p##2; wp[3 * STRIDE + lane] = p##3; } }

        float A0, A1, A2, A3, Q0, Q1, Q2, Q3;
        LOADG(A, 0)
#pragma unroll
        for (int k = 0; k < 64; k += 8) {
            LOADG(Q, k + 4)
            WRITEG(A, k)
            if (k + 8 < 64) LOADG(A, k + 8)
            WRITEG(Q, k + 4)
        }
#undef LOADG
#undef WRITEG
    }
    __syncthreads();

    // ---- forward substitution (lane = bc), in place in Bs ----
    const int bc = tid;
    float* Brow = Bs + bc * STRIDE;
    const int s511 = 514 - i0;    // slot of Z col 511 (read before overwrite)
    const float z511 = (s511 >= 0 && s511 < SLOTS) ? Brow[s511] : 0.0f;

    float y1 = 0.f, y2 = 0.f, y3 = 0.f;
    const int nfb = (NRr + 7) >> 3;
    for (int cc = 0; cc < nfb; ++cc) {
        const int ri = cc << 3;
        const int ib = i0 + ri;
        float zb[11];
#pragma unroll
        for (int m = 0; m < 11; ++m) zb[m] = Brow[ri + m];   // over-read padded
        if (ib >= INT_LO && ib + 7 <= INT_HI) {
#pragma unroll
            for (int k = 0; k < 8; ++k) {
                const float btz = CW0 * zb[k + 3] + CW1 * zb[k + 2] + CW2 * zb[k + 1] + CW3 * zb[k];
                const float y = (btz - CL1 * y1 - CL2 * y2 - CL3 * y3) * CRD;
                if (ri + k < NRr) Brow[ri + k] = y;
                y3 = y2; y2 = y1; y1 = y;
            }
        } else {
#pragma unroll
            for (int k = 0; k < 8; ++k) {
                const int i = ib + k;
                const int it = i < M ? i : M - 1;
                const float4 w = *(const float4*)TBL.w4[it];
                const float4 l = *(const float4*)TBL.lb[it];
                float btz = w.x * zb[k + 3] + w.y * zb[k + 2] + w.z * zb[k + 1] + w.w * zb[k];
                const int q = it - 510;
                if (q >= 0) btz += TBL.we[q] * z511;
                const float y = (btz - l.y * y1 - l.z * y2 - l.w * y3) * l.x;
                if (ri + k < NRr) Brow[ri + k] = y;
                y3 = y2; y2 = y1; y1 = y;
            }
        }
    }

    // ---- backward substitution, coef overwrites y in place ----
    const int top = i_end - i0;
    float c1 = 0.f, c2 = 0.f, c3 = 0.f;
    const int nbb = (NRb + 7) >> 3;
    for (int cc = 0; cc < nbb; ++cc) {
        const int ib = i_end - (cc << 3);
        float zb[8];
#pragma unroll
        for (int k = 0; k < 8; ++k) {
            int s = top - (cc << 3) - k;
            zb[k] = Brow[s < 0 ? 0 : s];
        }
        if (ib - 7 >= INT_LO && ib <= INT_HI) {
#pragma unroll
            for (int k = 0; k < 8; ++k) {
                const int i = ib - k;
                const float c = (zb[k] - CL1 * c1 - CL2 * c2 - CL3 * c3) * CRD;
                if ((cc << 3) + k < NRb) Brow[i - i0] = c;
                c3 = c2; c2 = c1; c1 = c;
            }
        } else {
#pragma unroll
            for (int k = 0; k < 8; ++k) {
                const int i = ib - k;
                const int it = i < 0 ? 0 : i;
                const float rd = TBL.lb[it][0];
                const float e1 = TBL.lb[it + 1][1];
                const float e2 = TBL.lb[it + 2][2];
                const float e3 = TBL.lb[it + 3][3];
                const float c = (zb[k] - e1 * c1 - e2 * c2 - e3 * c3) * rd;
                if ((cc << 3) + k < NRb) Brow[i - i0] = c;
                c3 = c2; c2 = c1; c1 = c;
            }
        }
    }
    __syncthreads();

    // ---- evaluate 8 points for own bc row (thread = bc), 2 float4 stores ----
    float Nv[8][4];
    int so[8];
#pragma unroll
    for (int j = 0; j < 8; ++j) {
        const int n = ns + j;
        const float xe = -1.0f + 2.0f * (float)n / 8191.0f;
        int off = (int)((xe + 1.0f) * 255.5f);
        off = off < 0 ? 0 : (off > NX - 2 ? NX - 2 : off);
        deboor3(xe, off + 3, Nv[j]);
        so[j] = off - i0;          // >= e_lo - i0 >= 0
    }
    const float* Cr = Bs + tid * STRIDE;
    float4 r0, r1;
    r0.x = Nv[0][0] * Cr[so[0]] + Nv[0][1] * Cr[so[0] + 1] + Nv[0][2] * Cr[so[0] + 2] + Nv[0][3] * Cr[so[0] + 3];
    r0.y = Nv[1][0] * Cr[so[1]] + Nv[1][1] * Cr[so[1] + 1] + Nv[1][2] * Cr[so[1] + 2] + Nv[1][3] * Cr[so[1] + 3];
    r0.z = Nv[2][0] * Cr[so[2]] + Nv[2][1] * Cr[so[2] + 1] + Nv[2][2] * Cr[so[2] + 2] + Nv[2][3] * Cr[so[2] + 3];
    r0.w = Nv[3][0] * Cr[so[3]] + Nv[3][1] * Cr[so[3] + 1] + Nv[3][2] * Cr[so[3] + 2] + Nv[3][3] * Cr[so[3] + 3];
    r1.x = Nv[4][0] * Cr[so[4]] + Nv[4][1] * Cr[so[4] + 1] + Nv[4][2] * Cr[so[4] + 2] + Nv[4][3] * Cr[so[4] + 3];
    r1.y = Nv[5][0] * Cr[so[5]] + Nv[5][1] * Cr[so[5] + 1] + Nv[5][2] * Cr[so[5] + 2] + Nv[5][3] * Cr[so[5] + 3];
    r1.z = Nv[6][0] * Cr[so[6]] + Nv[6][1] * Cr[so[6] + 1] + Nv[6][2] * Cr[so[6] + 2] + Nv[6][3] * Cr[so[6] + 3];
    r1.w = Nv[7][0] * Cr[so[7]] + Nv[7][1] * Cr[so[7] + 1] + Nv[7][2] * Cr[so[7] + 2] + Nv[7][3] * Cr[so[7] + 3];
    float* op = out + (size_t)tid * NE + ns;
    *(float4*)op = r0;
    *(float4*)(op + 4) = r1;
}

}  // namespace

extern "C" void kernel_launch(void* const* d_in, const int* in_sizes, int n_in,
                              void* d_out, int out_size, void* d_ws, size_t ws_size,
                              hipStream_t stream) {
    const float* Z = (const float*)d_in[0];
    float* out = (float*)d_out;
    (void)d_ws; (void)ws_size;

    hipLaunchKernelGGL(spline_fused, dim3(NBLK), dim3(256), 0, stream, Z, out);
}

// Round 10
// 17.894 us; speedup vs baseline: 1.5053x; 1.5053x over previous
//
#include <hip/hip_runtime.h>
#include <math.h>

namespace {

constexpr int NX  = 512;    // data points
constexpr int M   = 514;    // basis functions
constexpr int NE  = 8192;   // eval points
constexpr int NBC = 256;    // batch*channels
constexpr int WARM = 12;    // warm-up rows (rel err ~0.268^12 ~ 1e-7, threshold 9e-2)

constexpr int NBLK = 512;   // one block per 16 eval points (round-8 optimum)
constexpr int PPB  = NE / NBLK;     // 16
constexpr int CHUNKS = 9;   // float4 chunks staged per bc row
constexpr int SLOTS  = CHUNKS * 4; // 36 staged columns (window <= 30 rows + 3 taps + 3 align)
constexpr int STRIDE = 37;  // odd -> <=2-way LDS bank conflicts (free)

// ---------------------------------------------------------------------------
// Compile-time tables: basis weights and banded Cholesky factor (double math).
// ---------------------------------------------------------------------------
constexpr double dknot(int j) {
    int c = j - 3;
    c = c < 0 ? 0 : (c > NX - 1 ? NX - 1 : c);
    return -1.0 + 2.0 * (double)c / 511.0;
}

constexpr double csqrt(double x) {
    double r = x > 1.0 ? x : 1.0;
    for (int k = 0; k < 50; ++k) r = 0.5 * (r + x / r);
    return r;
}

struct Tables {
    alignas(16) float lb[M + 3][4];  // rd=1/diag, l1, l2, l3 (3 zero pad rows)
    alignas(16) float w4[M][4];      // w4[i][r] = weight of Z[i-r] in Btz[i] (0 if OOR)
    float we[4];                     // weight of Z[511] in Btz[510+q]
};

constexpr Tables make_tables() {
    Tables T{};
    double bx[NX][4] = {};
    for (int n = 0; n < NX; ++n) {
        const int off = n < NX - 1 ? n : NX - 2;
        const double x = -1.0 + 2.0 * (double)n / 511.0;
        double N[4] = {1.0, 0.0, 0.0, 0.0};
        for (int d = 1; d <= 3; ++d) {
            double saved = 0.0;
            for (int r = 0; r < d; ++r) {
                const double tr = dknot(off + 3 + r + 1);
                const double tl = dknot(off + 3 + r + 1 - d);
                const double temp = N[r] / (tr - tl);
                N[r] = saved + (tr - x) * temp;
                saved = (x - tl) * temp;
            }
            N[d] = saved;
        }
        for (int r = 0; r < 4; ++r) bx[n][r] = N[r];
    }
    double A[M][4] = {};
    for (int i = 0; i < M; ++i) {
        double a0 = 1e-3, a1 = 0.0, a2 = 0.0, a3 = 0.0;
        const int nlo = i - 3 < 0 ? 0 : i - 3;
        const int nhi = i + 1 > NX - 1 ? NX - 1 : i + 1;
        for (int n = nlo; n <= nhi; ++n) {
            const int off = n < NX - 1 ? n : NX - 2;
            const int ri = i - off;
            if (ri < 0 || ri > 3) continue;
            const double bi = bx[n][ri];
            a0 += bi * bx[n][ri];
            if (ri >= 1) a1 += bi * bx[n][ri - 1];
            if (ri >= 2) a2 += bi * bx[n][ri - 2];
            if (ri >= 3) a3 += bi * bx[n][ri - 3];
        }
        A[i][0] = a0; A[i][1] = a1; A[i][2] = a2; A[i][3] = a3;
    }
    {
        double rd1 = 0.0, l1p = 0.0, l2p = 0.0, rd2 = 0.0, l1pp = 0.0, rd3 = 0.0;
        for (int i = 0; i < M; ++i) {
            const double l3 = A[i][3] * rd3;
            const double l2 = (A[i][2] - l3 * l1pp) * rd2;
            const double l1 = (A[i][1] - l3 * l2p - l2 * l1p) * rd1;
            const double s  = A[i][0] - l3 * l3 - l2 * l2 - l1 * l1;
            const double rd = 1.0 / csqrt(s);
            T.lb[i][0] = (float)rd; T.lb[i][1] = (float)l1;
            T.lb[i][2] = (float)l2; T.lb[i][3] = (float)l3;
            rd3 = rd2; rd2 = rd1; rd1 = rd;
            l1pp = l1p; l1p = l1; l2p = l2;
        }
    }
    for (int i = 0; i < M; ++i)
        for (int r = 0; r < 4; ++r) {
            const int n = i - r;
            T.w4[i][r] = (n >= 0 && n <= NX - 2) ? (float)bx[n][r] : 0.0f;
        }
    for (int q = 0; q < 4; ++q) T.we[q] = (float)bx[NX - 1][q];
    return T;
}

__constant__ Tables TBL = make_tables();

// interior (Toeplitz / converged) constants as compile-time immediates
constexpr Tables HT = make_tables();
constexpr float CW0 = HT.w4[256][0], CW1 = HT.w4[256][1], CW2 = HT.w4[256][2], CW3 = HT.w4[256][3];
constexpr float CRD = HT.lb[256][0], CL1 = HT.lb[256][1], CL2 = HT.lb[256][2], CL3 = HT.lb[256][3];
constexpr int INT_LO = 48, INT_HI = 462;

// interval index of eval point n (single fp32 path everywhere)
__device__ __forceinline__ int offf(int n) {
    const float xe = -1.0f + 2.0f * (float)n / 8191.0f;
    int off = (int)((xe + 1.0f) * 255.5f);
    return off < 0 ? 0 : (off > NX - 2 ? NX - 2 : off);
}

__device__ __forceinline__ float knotf(int j) {
    int c = j - 3;
    c = c < 0 ? 0 : (c > NX - 1 ? NX - 1 : c);
    return -1.0f + 2.0f * (float)c / 511.0f;
}

__device__ __forceinline__ void deboor3(float x, int j, float N[4]) {
    N[0] = 1.0f; N[1] = 0.0f; N[2] = 0.0f; N[3] = 0.0f;
#pragma unroll
    for (int d = 1; d <= 3; ++d) {
        float saved = 0.0f;
#pragma unroll
        for (int r = 0; r < 3; ++r) {
            if (r < d) {
                const float tr = knotf(j + r + 1);
                const float tl = knotf(j + r + 1 - d);
                const float temp = N[r] / (tr - tl);
                N[r] = saved + (tr - x) * temp;
                saved = (x - tl) * temp;
            }
        }
        N[d] = saved;
    }
}

// ---------------------------------------------------------------------------
// Single fused kernel. Block b: eval points [b*16, b*16+16) x all 256 bc.
// Stage the Z window with 9 float4 loads/thread (8 coalesced chunks + 1
// remainder) into LDS (row per bc, stride 37, slot shift d for alignment),
// run warm-up fwd+bwd banded substitution per-lane in LDS, evaluate from
// LDS coef with float4 stores. 38 KB LDS.
// ---------------------------------------------------------------------------
__global__ __launch_bounds__(256) void spline_fused(const float* __restrict__ Z,
                                                    float* __restrict__ out) {
    __shared__ float Bs[NBC * STRIDE + 8];   // +8 pad for fwd over-read
    const int tid = threadIdx.x;
    const int b = blockIdx.x;
    const int ns = b * PPB;

    // wave-uniform geometry
    const int e_lo = offf(ns);                    // first coef row eval needs
    const int e_hi = offf(ns + PPB - 1) + 3;      // last coef row eval needs
    int i0 = e_lo - WARM;  i0 = i0 < 0 ? 0 : i0;  // forward start (exact if 0)
    int i_end = e_hi + WARM;  i_end = i_end > M - 1 ? M - 1 : i_end;
    const int n0 = i0 - 3;                        // first needed Z column
    const int n0a = n0 & ~3;                      // aligned staging base
    const int d = n0 - n0a;                       // slot shift 0..3 (wave-uniform)
    const int NRr = i_end - i0 + 1;               // forward rows  (<= 30)
    const int NRb = i_end - e_lo + 1;             // backward rows (<= 18)

    // ---- stage: 9 float4 loads/thread; 8 coalesced chunk loads + 1 remainder
    {
        const int wid = tid >> 6, lane = tid & 63;
        const int rsub = lane >> 3;    // row within 8-row group
        const int ch = lane & 7;       // float4 chunk 0..7
        int cb = n0a + (ch << 2);
        cb = cb < 0 ? 0 : (cb > NX - 4 ? NX - 4 : cb);  // clamped; OOR slots have zero weight
        int c8 = n0a + 32;
        c8 = c8 < 0 ? 0 : (c8 > NX - 4 ? NX - 4 : c8);

        float4 v[8], v8;
#pragma unroll
        for (int it = 0; it < 8; ++it) {
            const int row = (wid << 6) + (it << 3) + rsub;
            v[it] = *(const float4*)(Z + (size_t)row * NX + cb);
        }
        v8 = *(const float4*)(Z + (size_t)tid * NX + c8);
#pragma unroll
        for (int it = 0; it < 8; ++it) {
            const int row = (wid << 6) + (it << 3) + rsub;
            float* wp = Bs + row * STRIDE + (ch << 2);
            wp[0] = v[it].x; wp[1] = v[it].y; wp[2] = v[it].z; wp[3] = v[it].w;
        }
        {
            float* wp = Bs + tid * STRIDE + 32;
            wp[0] = v8.x; wp[1] = v8.y; wp[2] = v8.z; wp[3] = v8.w;
        }
    }
    __syncthreads();

    // ---- forward substitution (lane = bc), in place in Bs ----
    // Brow includes the alignment shift d: Brow[s] = column (n0 + s) before
    // overwrite; slot ri holds col i0-3+ri -> y_i -> coef_i as data dies.
    const int bc = tid;
    float* Brow = Bs + bc * STRIDE + d;
    const int s511 = 511 - n0;    // slot of Z col 511 (read before overwrite)
    const float z511 = (s511 >= 0 && s511 < SLOTS - d) ? Brow[s511] : 0.0f;

    float y1 = 0.f, y2 = 0.f, y3 = 0.f;
    const int nfb = (NRr + 7) >> 3;
    for (int cc = 0; cc < nfb; ++cc) {
        const int ri = cc << 3;
        const int ib = i0 + ri;
        float zb[11];
#pragma unroll
        for (int m = 0; m < 11; ++m) zb[m] = Brow[ri + m];   // over-read padded
        if (ib >= INT_LO && ib + 7 <= INT_HI) {
#pragma unroll
            for (int k = 0; k < 8; ++k) {
                const float btz = CW0 * zb[k + 3] + CW1 * zb[k + 2] + CW2 * zb[k + 1] + CW3 * zb[k];
                const float y = (btz - CL1 * y1 - CL2 * y2 - CL3 * y3) * CRD;
                if (ri + k < NRr) Brow[ri + k] = y;
                y3 = y2; y2 = y1; y1 = y;
            }
        } else {
#pragma unroll
            for (int k = 0; k < 8; ++k) {
                const int i = ib + k;
                const int it = i < M ? i : M - 1;
                const float4 w = *(const float4*)TBL.w4[it];
                const float4 l = *(const float4*)TBL.lb[it];
                float btz = w.x * zb[k + 3] + w.y * zb[k + 2] + w.z * zb[k + 1] + w.w * zb[k];
                const int q = it - 510;
                if (q >= 0) btz += TBL.we[q] * z511;
                const float y = (btz - l.y * y1 - l.z * y2 - l.w * y3) * l.x;
                if (ri + k < NRr) Brow[ri + k] = y;
                y3 = y2; y2 = y1; y1 = y;
            }
        }
    }

    // ---- backward substitution, coef overwrites y in place ----
    const int top = i_end - i0;
    float c1 = 0.f, c2 = 0.f, c3 = 0.f;
    const int nbb = (NRb + 7) >> 3;
    for (int cc = 0; cc < nbb; ++cc) {
        const int ib = i_end - (cc << 3);
        float zb[8];
#pragma unroll
        for (int k = 0; k < 8; ++k) {
            int s = top - (cc << 3) - k;
            zb[k] = Brow[s < 0 ? 0 : s];
        }
        if (ib - 7 >= INT_LO && ib <= INT_HI) {
#pragma unroll
            for (int k = 0; k < 8; ++k) {
                const int i = ib - k;
                const float c = (zb[k] - CL1 * c1 - CL2 * c2 - CL3 * c3) * CRD;
                if ((cc << 3) + k < NRb) Brow[i - i0] = c;
                c3 = c2; c2 = c1; c1 = c;
            }
        } else {
#pragma unroll
            for (int k = 0; k < 8; ++k) {
                const int i = ib - k;
                const int it = i < 0 ? 0 : i;
                const float rd = TBL.lb[it][0];
                const float e1 = TBL.lb[it + 1][1];
                const float e2 = TBL.lb[it + 2][2];
                const float e3 = TBL.lb[it + 3][3];
                const float c = (zb[k] - e1 * c1 - e2 * c2 - e3 * c3) * rd;
                if ((cc << 3) + k < NRb) Brow[i - i0] = c;
                c3 = c2; c2 = c1; c1 = c;
            }
        }
    }
    __syncthreads();

    // ---- evaluate 16 points x 256 bc from LDS coef, float4 stores ----
    const int q  = tid & 3;        // quad of 4 points
    const int bc0 = tid >> 2;      // 0..63
    float Nv[4][4];
    int so[4];
#pragma unroll
    for (int j = 0; j < 4; ++j) {
        const int n = ns + (q << 2) + j;
        const float xe = -1.0f + 2.0f * (float)n / 8191.0f;
        int off = (int)((xe + 1.0f) * 255.5f);
        off = off < 0 ? 0 : (off > NX - 2 ? NX - 2 : off);
        deboor3(xe, off + 3, Nv[j]);
        so[j] = off - i0;          // >= e_lo - i0 >= 0
    }
#pragma unroll
    for (int it = 0; it < 4; ++it) {
        const int bcw = bc0 + (it << 6);
        const float* Cr = Bs + bcw * STRIDE + d;
        float4 r;
        r.x = Nv[0][0] * Cr[so[0]] + Nv[0][1] * Cr[so[0] + 1] + Nv[0][2] * Cr[so[0] + 2] + Nv[0][3] * Cr[so[0] + 3];
        r.y = Nv[1][0] * Cr[so[1]] + Nv[1][1] * Cr[so[1] + 1] + Nv[1][2] * Cr[so[1] + 2] + Nv[1][3] * Cr[so[1] + 3];
        r.z = Nv[2][0] * Cr[so[2]] + Nv[2][1] * Cr[so[2] + 1] + Nv[2][2] * Cr[so[2] + 2] + Nv[2][3] * Cr[so[2] + 3];
        r.w = Nv[3][0] * Cr[so[3]] + Nv[3][1] * Cr[so[3] + 1] + Nv[3][2] * Cr[so[3] + 2] + Nv[3][3] * Cr[so[3] + 3];
        *(float4*)(out + (size_t)bcw * NE + ns + (q << 2)) = r;
    }
}

}  // namespace

extern "C" void kernel_launch(void* const* d_in, const int* in_sizes, int n_in,
                              void* d_out, int out_size, void* d_ws, size_t ws_size,
                              hipStream_t stream) {
    const float* Z = (const float*)d_in[0];
    float* out = (float*)d_out;
    (void)d_ws; (void)ws_size;

    hipLaunchKernelGGL(spline_fused, dim3(NBLK), dim3(256), 0, stream, Z, out);
}